// Round 1
// baseline (380.604 us; speedup 1.0000x reference)
//
#include <hip/hip_runtime.h>
#include <math.h>

#define BLOCK 256
#define PBOUND 0.99999f /* 1 - 1e-5 */

__device__ __forceinline__ float artanh_clamped(float n) {
    float z = fminf(n, PBOUND);
    return 0.5f * __logf((1.0f + z) / (1.0f - z));
}

// logmap0 of a register vector v[D] -> LDS column (stride BLOCK floats)
template <int D>
__device__ __forceinline__ void logmap_to_lds(const float* v, float* u_col) {
    float n2 = 0.0f;
#pragma unroll
    for (int k = 0; k < D; ++k) n2 = fmaf(v[k], v[k], n2);
    float n = fmaxf(sqrtf(n2), 1e-15f);
    float s = artanh_clamped(n) / n;
#pragma unroll
    for (int k = 0; k < D; ++k) u_col[k * BLOCK] = v[k] * s;
}

// y[J] = (lds column u)[K] @ W[K][J]   (W row-major [K][J], wave-uniform -> s_load)
template <int K, int J>
__device__ __forceinline__ void matvec(const float* __restrict__ W,
                                       const float* u_col, float* y) {
#pragma unroll
    for (int j = 0; j < J; ++j) y[j] = 0.0f;
#pragma unroll 2
    for (int k = 0; k < K; ++k) {
        float uk = u_col[k * BLOCK];
        const float* wr = W + k * J;
#pragma unroll
        for (int j = 0; j < J; ++j) y[j] = fmaf(uk, wr[j], y[j]);
    }
}

template <int D>
__device__ __forceinline__ void expmap_inplace(float* y) {
    float n2 = 0.0f;
#pragma unroll
    for (int k = 0; k < D; ++k) n2 = fmaf(y[k], y[k], n2);
    float n = fmaxf(sqrtf(n2), 1e-15f);
    float s = tanhf(n) / n;
#pragma unroll
    for (int k = 0; k < D; ++k) y[k] *= s;
}

// x <- mobius_add(x, y), y in registers
template <int D>
__device__ __forceinline__ void mobius_add_inplace(float* x, const float* y) {
    float x2 = 0.0f, y2 = 0.0f, xy = 0.0f;
#pragma unroll
    for (int k = 0; k < D; ++k) {
        x2 = fmaf(x[k], x[k], x2);
        y2 = fmaf(y[k], y[k], y2);
        xy = fmaf(x[k], y[k], xy);
    }
    float a = 1.0f + 2.0f * xy + y2;
    float b = 1.0f - x2;
    float den = fmaxf(fmaf(x2, y2, 1.0f + 2.0f * xy), 1e-15f);
    float inv = 1.0f / den;
#pragma unroll
    for (int k = 0; k < D; ++k) x[k] = (a * x[k] + b * y[k]) * inv;
}

// x <- mobius_add(x, bias) with bias a wave-uniform global row (s_load path)
template <int D>
__device__ __forceinline__ void mobius_add_bias(float* x, const float* __restrict__ bias) {
    float x2 = 0.0f, y2 = 0.0f, xy = 0.0f;
#pragma unroll
    for (int k = 0; k < D; ++k) {
        float bk = bias[k];
        x2 = fmaf(x[k], x[k], x2);
        y2 = fmaf(bk, bk, y2);
        xy = fmaf(x[k], bk, xy);
    }
    float a = 1.0f + 2.0f * xy + y2;
    float b = 1.0f - x2;
    float den = fmaxf(fmaf(x2, y2, 1.0f + 2.0f * xy), 1e-15f);
    float inv = 1.0f / den;
#pragma unroll
    for (int k = 0; k < D; ++k) x[k] = (a * x[k] + b * bias[k]) * inv;
}

__global__ void __launch_bounds__(BLOCK) poincare_mlp_kernel(
    const float* __restrict__ x1, const float* __restrict__ x2,
    const float* __restrict__ Wc1, const float* __restrict__ Wc2,
    const float* __restrict__ bc, const float* __restrict__ W0,
    const float* __restrict__ b0, const float* __restrict__ W1,
    const float* __restrict__ b1, float* __restrict__ out, int nrows) {
    // Per-thread private column: u_lds[k*BLOCK + tid]. Consecutive lanes ->
    // consecutive banks (2 lanes/bank, free). No cross-thread sharing -> no barriers.
    __shared__ float u_lds[64 * BLOCK]; // 64 KB -> 2 blocks/CU
    const int tid = threadIdx.x;
    const int row = blockIdx.x * BLOCK + tid;
    if (row >= nrows) return;
    float* u_col = u_lds + tid;

    float h1[64], h2[64];

    // ---- branch 1: expmap0(logmap0(x1) @ Wc1)
    {
        float v[32];
        const float4* p = (const float4*)(x1 + (size_t)row * 32);
#pragma unroll
        for (int i = 0; i < 8; ++i) {
            float4 t = p[i];
            v[4 * i + 0] = t.x; v[4 * i + 1] = t.y;
            v[4 * i + 2] = t.z; v[4 * i + 3] = t.w;
        }
        logmap_to_lds<32>(v, u_col);
    }
    matvec<32, 64>(Wc1, u_col, h1);
    expmap_inplace<64>(h1);

    // ---- branch 2
    {
        float v[32];
        const float4* p = (const float4*)(x2 + (size_t)row * 32);
#pragma unroll
        for (int i = 0; i < 8; ++i) {
            float4 t = p[i];
            v[4 * i + 0] = t.x; v[4 * i + 1] = t.y;
            v[4 * i + 2] = t.z; v[4 * i + 3] = t.w;
        }
        logmap_to_lds<32>(v, u_col);
    }
    matvec<32, 64>(Wc2, u_col, h2);
    expmap_inplace<64>(h2);

    // ---- concat: h = mobius_add(mobius_add(h1, h2), bc)
    mobius_add_inplace<64>(h1, h2);
    mobius_add_bias<64>(h1, bc);

    // ---- layer 0: poincare_linear(h, W0, b0)
    logmap_to_lds<64>(h1, u_col);
    matvec<64, 64>(W0, u_col, h2);
    expmap_inplace<64>(h2);
    mobius_add_bias<64>(h2, b0);

    // ---- layer 1: poincare_linear(h, W1, b1)
    logmap_to_lds<64>(h2, u_col);
    float y[32];
    matvec<64, 32>(W1, u_col, y);
    expmap_inplace<32>(y);
    mobius_add_bias<32>(y, b1);

    float4* q = (float4*)(out + (size_t)row * 32);
#pragma unroll
    for (int i = 0; i < 8; ++i) {
        float4 t;
        t.x = y[4 * i + 0]; t.y = y[4 * i + 1];
        t.z = y[4 * i + 2]; t.w = y[4 * i + 3];
        q[i] = t;
    }
}

extern "C" void kernel_launch(void* const* d_in, const int* in_sizes, int n_in,
                              void* d_out, int out_size, void* d_ws, size_t ws_size,
                              hipStream_t stream) {
    const float* x1  = (const float*)d_in[0];
    const float* x2  = (const float*)d_in[1];
    const float* Wc1 = (const float*)d_in[2];
    const float* Wc2 = (const float*)d_in[3];
    const float* bc  = (const float*)d_in[4];
    const float* W0  = (const float*)d_in[5];
    const float* b0  = (const float*)d_in[6];
    const float* W1  = (const float*)d_in[7];
    const float* b1  = (const float*)d_in[8];
    float* out = (float*)d_out;

    const int nrows = in_sizes[0] / 32;
    const int nblocks = (nrows + BLOCK - 1) / BLOCK;
    poincare_mlp_kernel<<<nblocks, BLOCK, 0, stream>>>(
        x1, x2, Wc1, Wc2, bc, W0, b0, W1, b1, out, nrows);
}